// Round 11
// baseline (619.108 us; speedup 1.0000x reference)
//
#include <hip/hip_runtime.h>
#include <hip/hip_bf16.h>
#include <stdint.h>

#define BB   2
#define NN   2048
#define BN   (BB*NN)
#define KTOP 48
#define EIN  416
#define EF   128

typedef __attribute__((ext_vector_type(8))) short s8v;
typedef __attribute__((ext_vector_type(4))) float f32x4;
typedef __attribute__((ext_vector_type(4))) unsigned int u32x4;
typedef unsigned short u16;
typedef unsigned int u32;
typedef unsigned long long u64;

__device__ __constant__ int cPA[25] = {1,0,2,3,4,1,1,1,1,0,0,0,4,4,3,0,2,3,4,2,3,4,2,3,2};
__device__ __constant__ int cPB[25] = {1,0,2,3,4,0,2,3,4,2,3,4,2,3,2,1,1,1,1,0,0,0,4,4,3};

__device__ __forceinline__ u16 bf16u(float x) {
  __hip_bfloat16 h = __float2bfloat16(x);
  return *reinterpret_cast<u16*>(&h);
}
// hardware packed f32->bf16 (RNE), 1 instr for 2 values
__device__ __forceinline__ u32 cvtpk(float lo, float hi) {
  u32 r;
  asm("v_cvt_pk_bf16_f32 %0, %1, %2" : "=v"(r) : "v"(lo), "v"(hi));
  return r;
}

// ---------------- prep: padded atoms [BN][5][4], Ca pack [BN][4], W_edge MFMA-tiled bf16 ----
__global__ __launch_bounds__(256) void prep_kernel(const float* __restrict__ X,
                                                   const float* __restrict__ W_edge,
                                                   float* __restrict__ atoms5p,
                                                   float* __restrict__ capack4,
                                                   u16* __restrict__ wtf) {
  int tid = blockIdx.x * 256 + threadIdx.x;
  if (tid < EIN * EF) {
    int k = tid >> 7, n = tid & 127;
    wtf[((size_t)(k >> 3)) * 1024 + n * 8 + (k & 7)] = bf16u(W_edge[tid]);
  } else if (tid < EIN * EF + BN) {
    int idx = tid - EIN * EF;
    const float* x = X + (size_t)idx * 12;
    float Nx = x[0], Ny = x[1], Nz = x[2];
    float Cax = x[3], Cay = x[4], Caz = x[5];
    float Cx = x[6], Cy = x[7], Cz = x[8];
    float Ox = x[9], Oy = x[10], Oz = x[11];
    float bx = Cax - Nx, by = Cay - Ny, bz = Caz - Nz;
    float cx = Cx - Cax, cy = Cy - Cay, cz = Cz - Caz;
    float ax = by * cz - bz * cy;
    float ay = bz * cx - bx * cz;
    float az = bx * cy - by * cx;
    float Cbx = -0.58273431f * ax + 0.56802827f * bx - 0.54067466f * cx + Cax;
    float Cby = -0.58273431f * ay + 0.56802827f * by - 0.54067466f * cy + Cay;
    float Cbz = -0.58273431f * az + 0.56802827f * bz - 0.54067466f * cz + Caz;
    f32x4* o = (f32x4*)(atoms5p + (size_t)idx * 20);
    o[0] = (f32x4){Nx, Ny, Nz, 0.f};
    o[1] = (f32x4){Cax, Cay, Caz, 0.f};
    o[2] = (f32x4){Cx, Cy, Cz, 0.f};
    o[3] = (f32x4){Ox, Oy, Oz, 0.f};
    o[4] = (f32x4){Cbx, Cby, Cbz, 0.f};
    *(f32x4*)(capack4 + (size_t)idx * 4) = (f32x4){Cax, Cay, Caz, 0.f};
  }
}

// exclusive block scan over 256 threads
__device__ __forceinline__ u32 blockExclScan(u32 v, u32* scanw, int t) {
  int lane = t & 63, w = t >> 6;
  u32 inc = v;
#pragma unroll
  for (int off = 1; off < 64; off <<= 1) {
    u32 o = __shfl_up(inc, off);
    if (lane >= off) inc += o;
  }
  if (lane == 63) scanw[w] = inc;
  __syncthreads();
  u32 base = 0;
  for (int ww = 0; ww < w; ++ww) base += scanw[ww];
  __syncthreads();
  return base + inc - v;
}

template<int NB, bool CHKPREF>
__device__ __forceinline__ void radix_round(u32* hist, u32* scanw, u32* selinfo, int t,
                                            const u32* kv, u32 pref, int prefShift,
                                            int binShift, u32 binMask, u32 r) {
  const int PB = NB / 256;
#pragma unroll
  for (int q = 0; q < PB / 4; ++q)
    *(u32x4*)&hist[t * PB + q * 4] = (u32x4){0, 0, 0, 0};
  __syncthreads();
#pragma unroll
  for (int s = 0; s < 8; ++s) {
    bool ok = (!CHKPREF) || ((kv[s] >> prefShift) == pref);
    if (ok) atomicAdd(&hist[(kv[s] >> binShift) & binMask], 1u);
  }
  __syncthreads();
  u32 loc[PB];
  u32 sum = 0;
#pragma unroll
  for (int q = 0; q < PB / 4; ++q) {
    u32x4 lv = *(u32x4*)&hist[t * PB + q * 4];
    loc[q * 4 + 0] = lv.x; loc[q * 4 + 1] = lv.y;
    loc[q * 4 + 2] = lv.z; loc[q * 4 + 3] = lv.w;
    sum += lv.x + lv.y + lv.z + lv.w;
  }
  int lane = t & 63, w = t >> 6;
  u32 inc = sum;
#pragma unroll
  for (int off = 1; off < 64; off <<= 1) {
    u32 o = __shfl_up(inc, off);
    if (lane >= off) inc += o;
  }
  if (lane == 63) scanw[w] = inc;
  __syncthreads();
  u32 base = 0;
  for (int ww = 0; ww < w; ++ww) base += scanw[ww];
  u32 c = base + inc - sum;
#pragma unroll
  for (int q = 0; q < PB; ++q) {
    u32 nc = c + loc[q];
    if (c < r && r <= nc) { selinfo[0] = (u32)(t * PB + q); selinfo[1] = r - c; }
    c = nc;
  }
  __syncthreads();
}

// ---------------- top-48 per row: exact radix select ----------------
__global__ __launch_bounds__(256) void topk_kernel(const float* __restrict__ capack4,
                                                   const float* __restrict__ mask,
                                                   float* __restrict__ dtop,
                                                   float* __restrict__ eidx_f) {
  __shared__ u32 hist[4096];
  __shared__ u32 scanw[4];
  __shared__ u32 selinfo[2];
  __shared__ float redf[4];
  __shared__ u64 win[64];

  int row = blockIdx.x;
  int b = row >> 11, i = row & (NN - 1);
  int t = threadIdx.x, lane = t & 63, w = t >> 6;
  const float* cab4 = capack4 + (size_t)b * NN * 4;
  const float* mrow = mask + (size_t)b * NN;
  f32x4 ci = *(const f32x4*)&cab4[(size_t)i * 4];
  float mi = mrow[i];
  f32x4 mk0 = *(const f32x4*)&mrow[t * 8];
  f32x4 mk1 = *(const f32x4*)&mrow[t * 8 + 4];

  float dvv[8], m2v[8];
  float lmax = 0.f;
#pragma unroll
  for (int s = 0; s < 8; ++s) {
    f32x4 cj = *(const f32x4*)&cab4[(size_t)(t * 8 + s) * 4];
    float dx = ci.x - cj.x, dy = ci.y - cj.y, dz = ci.z - cj.z;
    float d = sqrtf(dx * dx + dy * dy + dz * dz + 1e-6f);
    float mj = (s < 4) ? mk0[s] : mk1[s - 4];
    float m2 = mi * mj;
    float D = m2 * d;
    dvv[s] = D; m2v[s] = m2;
    lmax = fmaxf(lmax, D);
  }
#pragma unroll
  for (int off = 32; off >= 1; off >>= 1) lmax = fmaxf(lmax, __shfl_xor(lmax, off));
  if (lane == 0) redf[w] = lmax;
  __syncthreads();
  float rmax = fmaxf(fmaxf(redf[0], redf[1]), fmaxf(redf[2], redf[3]));

  u32 kv[8];
#pragma unroll
  for (int s = 0; s < 8; ++s)
    kv[s] = __float_as_uint(dvv[s] + (1.0f - m2v[s]) * rmax);

  u32 r = KTOP;
  radix_round<4096, false>(hist, scanw, selinfo, t, kv, 0, 0, 20, 0xFFFu, r);
  u32 sel1 = selinfo[0]; r = selinfo[1];
  radix_round<1024, true>(hist, scanw, selinfo, t, kv, sel1, 20, 10, 0x3FFu, r);
  u32 sel2 = selinfo[0]; r = selinfo[1];
  u32 pref12 = (sel1 << 10) | sel2;
  radix_round<1024, true>(hist, scanw, selinfo, t, kv, pref12, 10, 0, 0x3FFu, r);
  u32 sel3 = selinfo[0];
  u32 takeEq = selinfo[1];
  u32 T = (sel1 << 20) | (sel2 << 10) | sel3;

  u32 lcnt = 0, ecnt = 0;
#pragma unroll
  for (int s = 0; s < 8; ++s) { lcnt += (kv[s] < T); ecnt += (kv[s] == T); }
  u32 ebase = blockExclScan(ecnt, scanw, t);
  u32 taken = 0;
  if (ebase < takeEq) { u32 room = takeEq - ebase; taken = room < ecnt ? room : ecnt; }
  u32 wbase = blockExclScan(lcnt + taken, scanw, t);
  u32 slot = wbase, tleft = taken;
#pragma unroll
  for (int s = 0; s < 8; ++s) {
    u32 j = (u32)(t * 8 + s);
    if (kv[s] < T) {
      win[slot++] = ((u64)kv[s] << 32) | j;
    } else if (kv[s] == T && tleft) {
      win[slot++] = ((u64)kv[s] << 32) | j;
      tleft--;
    }
  }
  __syncthreads();

  if (w == 0) {
    u64 key = (lane < KTOP) ? win[lane] : ~0ull;
#pragma unroll
    for (int k = 2; k <= 64; k <<= 1) {
#pragma unroll
      for (int jj = k >> 1; jj >= 1; jj >>= 1) {
        u64 p = __shfl_xor(key, jj);
        bool lowerl = (lane & jj) == 0;
        bool asc = (lane & k) == 0;
        u64 mn = p < key ? p : key;
        u64 mx = p < key ? key : p;
        key = (lowerl == asc) ? mn : mx;
      }
    }
    if (lane < KTOP) {
      u32 j = (u32)(key & 0xffffffffu);
      eidx_f[row * KTOP + lane] = (float)j;
      dtop[row * KTOP + lane] = __uint_as_float((u32)(key >> 32));
    }
  }
}

// RBF 8-vector via geometric recurrence + hw packed bf16 convert (~25 VALU ops)
__device__ __forceinline__ s8v rbf8(float D, float mu0) {
  float Dc = fminf(D, 40.0f);
  float t0 = (Dc - mu0) * 0.8f;
  float v0 = __expf(-t0 * t0);
  float g = __expf(fmaf(2.13333333f, t0, -1.13777778f));
  const float C = 0.10273985f;
  float v1 = v0 * g; g *= C;
  float v2 = v1 * g; g *= C;
  float v3 = v2 * g; g *= C;
  float v4 = v3 * g; g *= C;
  float v5 = v4 * g; g *= C;
  float v6 = v5 * g; g *= C;
  float v7 = v6 * g;
  union { u32x4 u; s8v s; } cv;
  cv.u = (u32x4){cvtpk(v0, v1), cvtpk(v2, v3), cvtpk(v4, v5), cvtpk(v6, v7)};
  return cv.s;
}

// ---------------- edge: wave = (residue, n-half). 48 rows x 64 cols per wave. ----------------
// Setup computes D[3][12] + af0[3] FIRST (I/J regs die before acc created): peak ~103 regs
// in setup, ~115 in main loop. launch_bounds(256,3) -> ~168-reg cap, zero spill risk.
__global__ __launch_bounds__(256, 3) void edge_kernel(const float* __restrict__ atoms5p,
                                                      const u16* __restrict__ wtf,
                                                      const float* __restrict__ eidx_f,
                                                      const float* __restrict__ dtop,
                                                      const int* __restrict__ Ridx,
                                                      const int* __restrict__ chains,
                                                      const float* __restrict__ Wpos,
                                                      const float* __restrict__ bpos,
                                                      const float* __restrict__ bedge,
                                                      float* __restrict__ Eout) {
  static constexpr int kPA[25] = {1,0,2,3,4,1,1,1,1,0,0,0,4,4,3,0,2,3,4,2,3,4,2,3,2};
  static constexpr int kPB[25] = {1,0,2,3,4,0,2,3,4,2,3,4,2,3,2,1,1,1,1,0,0,0,4,4,3};

  int t = threadIdx.x;
  int lane = t & 63, w = t >> 6;
  int lr = lane & 15, lg = lane >> 4;
  bool hi = (lg >= 2);

  int task = blockIdx.x * 4 + w;            // 8192 tasks = BN * 2
  int row = task >> 1, nh = task & 1;       // n-half: cols nh*64 .. nh*64+63
  int b = row >> 11, i = row & (NN - 1);
  const float* atomsB = atoms5p + (size_t)b * NN * 20;

  int Ri = Ridx[b * NN + i];
  int chi = chains[b * NN + i];

  const float MU8 = 12.6666667f;
  float mu0 = (lg & 1) ? MU8 : 2.0f;
  int colbase = nh * 64 + lr;

  float D[3][12];
  s8v af0[3];

  // ---- setup: ALL distances + kc=0 fragments before any accumulator exists ----
  {
    f32x4 I[5];
#pragma unroll
    for (int a = 0; a < 5; ++a)
      I[a] = *(const f32x4*)&atomsB[(size_t)i * 20 + a * 4];
#pragma unroll
    for (int mt = 0; mt < 3; ++mt) {
      int kk = mt * 16 + lr;
      int j = (int)eidx_f[(size_t)row * KTOP + kk];
      float dtv = dtop[(size_t)row * KTOP + kk];
      {
        f32x4 J[5];
#pragma unroll
        for (int a = 0; a < 5; ++a)
          J[a] = *(const f32x4*)&atomsB[(size_t)j * 20 + a * 4];
#pragma unroll
        for (int q = 0; q < 12; ++q) {
          f32x4 Iv = hi ? I[kPA[2 * q + 2]] : I[kPA[2 * q + 1]];
          f32x4 Jv = hi ? J[kPB[2 * q + 2]] : J[kPB[2 * q + 1]];
          float dx = Iv.x - Jv.x, dy = Iv.y - Jv.y, dz = Iv.z - Jv.z;
          D[mt][q] = __builtin_amdgcn_sqrtf(dx * dx + dy * dy + dz * dz + 1e-6f);
        }
      }
      if (lg < 2) {
        int Rj = Ridx[b * NN + j];
        int same = (chi == chains[b * NN + j]);
        int off = Ri - Rj + 32;
        off = off < 0 ? 0 : (off > 64 ? 64 : off);
        int drow = same ? off : 65;
        const float* wr = Wpos + drow * 16 + lg * 8;
        f32x4 w0 = *(const f32x4*)wr;
        f32x4 w1 = *(const f32x4*)(wr + 4);
        f32x4 b0 = *(const f32x4*)(bpos + lg * 8);
        f32x4 b1 = *(const f32x4*)(bpos + lg * 8 + 4);
        union { u32x4 u; s8v s; } cv;
        cv.u = (u32x4){cvtpk(w0.x + b0.x, w0.y + b0.y), cvtpk(w0.z + b0.z, w0.w + b0.w),
                       cvtpk(w1.x + b1.x, w1.y + b1.y), cvtpk(w1.z + b1.z, w1.w + b1.w)};
        af0[mt] = cv.s;
      } else {
        af0[mt] = rbf8(dtv, (lg == 2) ? 2.0f : MU8);
      }
    }
  }

  // ---- main loop kc = 0..12: B from L2, A generated in-register ----
  f32x4 acc0[4] = {}, acc1[4] = {}, acc2[4] = {};
#pragma unroll
  for (int kc = 0; kc < 13; ++kc) {
    s8v a0 = kc ? rbf8(D[0][kc - 1], mu0) : af0[0];
    s8v a1 = kc ? rbf8(D[1][kc - 1], mu0) : af0[1];
    s8v a2 = kc ? rbf8(D[2][kc - 1], mu0) : af0[2];
    const u16* bb = wtf + (size_t)(kc * 4 + lg) * 1024 + colbase * 8;
#pragma unroll
    for (int nt = 0; nt < 4; ++nt) {
      s8v bv = *(const s8v*)(bb + nt * 128);
      acc0[nt] = __builtin_amdgcn_mfma_f32_16x16x32_bf16(a0, bv, acc0[nt], 0, 0, 0);
      acc1[nt] = __builtin_amdgcn_mfma_f32_16x16x32_bf16(a1, bv, acc1[nt], 0, 0, 0);
      acc2[nt] = __builtin_amdgcn_mfma_f32_16x16x32_bf16(a2, bv, acc2[nt], 0, 0, 0);
    }
  }

  // ---- epilogue: bias + direct stores (16-lane groups write 64B contiguous) ----
  float bias[4];
#pragma unroll
  for (int nt = 0; nt < 4; ++nt) bias[nt] = bedge[nh * 64 + nt * 16 + lr];
  float* orow = Eout + (size_t)row * KTOP * EF + nh * 64 + lr;
#pragma unroll
  for (int qq = 0; qq < 4; ++qq) {
    float* p0 = orow + (size_t)(lg * 4 + qq) * EF;
    float* p1 = orow + (size_t)(16 + lg * 4 + qq) * EF;
    float* p2 = orow + (size_t)(32 + lg * 4 + qq) * EF;
#pragma unroll
    for (int nt = 0; nt < 4; ++nt) {
      p0[nt * 16] = acc0[nt][qq] + bias[nt];
      p1[nt * 16] = acc1[nt][qq] + bias[nt];
      p2[nt * 16] = acc2[nt][qq] + bias[nt];
    }
  }
}

extern "C" void kernel_launch(void* const* d_in, const int* in_sizes, int n_in,
                              void* d_out, int out_size, void* d_ws, size_t ws_size,
                              hipStream_t stream) {
  const float* X = (const float*)d_in[0];
  const float* mask = (const float*)d_in[1];
  const int* Ridx = (const int*)d_in[2];
  const int* chains = (const int*)d_in[3];
  const float* Wpos = (const float*)d_in[4];
  const float* bpos = (const float*)d_in[5];
  const float* Wedge = (const float*)d_in[6];
  const float* bedge = (const float*)d_in[7];

  float* Eout = (float*)d_out;
  float* EidxF = Eout + (size_t)BN * KTOP * EF;

  u16* wtf = (u16*)d_ws;                                   // 53248 u16
  float* atoms5p = (float*)((char*)d_ws + 53248 * 2);      // BN*20 f32
  float* capack4 = atoms5p + (size_t)BN * 20;              // BN*4 f32
  float* dtop = capack4 + (size_t)BN * 4;                  // BN*48 f32

  prep_kernel<<<(EIN * EF + BN + 255) / 256, 256, 0, stream>>>(X, Wedge, atoms5p, capack4, wtf);
  topk_kernel<<<BN, 256, 0, stream>>>(capack4, mask, dtop, EidxF);
  edge_kernel<<<BN * 2 / 4, 256, 0, stream>>>(atoms5p, wtf, EidxF, dtop, Ridx, chains, Wpos, bpos, bedge, Eout);
}

// Round 13
// 95.132 us; speedup vs baseline: 6.5079x; 6.5079x over previous
//
#include <hip/hip_runtime.h>
#include <hip/hip_bf16.h>
#include <stdint.h>

#define BB   2
#define NN   2048
#define BN   (BB*NN)
#define KTOP 48
#define EIN  416
#define EF   128

typedef __attribute__((ext_vector_type(8))) short s8v;
typedef __attribute__((ext_vector_type(4))) float f32x4;
typedef __attribute__((ext_vector_type(4))) unsigned int u32x4;
typedef unsigned char u8;
typedef unsigned short u16;
typedef unsigned int u32;
typedef unsigned long long u64;

__device__ __constant__ int cPA[25] = {1,0,2,3,4,1,1,1,1,0,0,0,4,4,3,0,2,3,4,2,3,4,2,3,2};
__device__ __constant__ int cPB[25] = {1,0,2,3,4,0,2,3,4,2,3,4,2,3,2,1,1,1,1,0,0,0,4,4,3};

// hardware packed f32->fp8 e4m3 (OCP on gfx950): writes 2 bytes into low/high half of dst
__device__ __forceinline__ u32 cvtpk_fp8(float a, float b, u32 old, bool hi) {
  u32 r = old;
  if (hi) asm("v_cvt_pk_fp8_f32 %0, %1, %2 op_sel:[0,0,1]" : "+v"(r) : "v"(a), "v"(b));
  else    asm("v_cvt_pk_fp8_f32 %0, %1, %2" : "+v"(r) : "v"(a), "v"(b));
  return r;
}

// ---------------- prep: padded atoms [BN][5][4], Ca pack [BN][4], W_edge fp8 MFMA-tiled ----
// wtf8 layout: byte for (k,n) at (k>>3)*1024 + n*8 + (k&7)  [13 kc-slices x 4KB]
__global__ __launch_bounds__(256) void prep_kernel(const float* __restrict__ X,
                                                   const float* __restrict__ W_edge,
                                                   float* __restrict__ atoms5p,
                                                   float* __restrict__ capack4,
                                                   u8* __restrict__ wtf8) {
  int tid = blockIdx.x * 256 + threadIdx.x;
  if (tid < EIN * EF / 4) {
    int n = tid & 127, kq = tid >> 7;       // kq 0..103
    int k0 = kq * 4;
    float w0 = W_edge[(k0 + 0) * 128 + n];
    float w1 = W_edge[(k0 + 1) * 128 + n];
    float w2 = W_edge[(k0 + 2) * 128 + n];
    float w3 = W_edge[(k0 + 3) * 128 + n];
    u32 v = cvtpk_fp8(w0, w1, 0u, false);
    v = cvtpk_fp8(w2, w3, v, true);
    *(u32*)&wtf8[(k0 >> 3) * 1024 + n * 8 + (k0 & 7)] = v;
  } else if (tid < EIN * EF / 4 + BN) {
    int idx = tid - EIN * EF / 4;
    const float* x = X + (size_t)idx * 12;
    float Nx = x[0], Ny = x[1], Nz = x[2];
    float Cax = x[3], Cay = x[4], Caz = x[5];
    float Cx = x[6], Cy = x[7], Cz = x[8];
    float Ox = x[9], Oy = x[10], Oz = x[11];
    float bx = Cax - Nx, by = Cay - Ny, bz = Caz - Nz;
    float cx = Cx - Cax, cy = Cy - Cay, cz = Cz - Caz;
    float ax = by * cz - bz * cy;
    float ay = bz * cx - bx * cz;
    float az = bx * cy - by * cx;
    float Cbx = -0.58273431f * ax + 0.56802827f * bx - 0.54067466f * cx + Cax;
    float Cby = -0.58273431f * ay + 0.56802827f * by - 0.54067466f * cy + Cay;
    float Cbz = -0.58273431f * az + 0.56802827f * bz - 0.54067466f * cz + Caz;
    f32x4* o = (f32x4*)(atoms5p + (size_t)idx * 20);
    o[0] = (f32x4){Nx, Ny, Nz, 0.f};
    o[1] = (f32x4){Cax, Cay, Caz, 0.f};
    o[2] = (f32x4){Cx, Cy, Cz, 0.f};
    o[3] = (f32x4){Ox, Oy, Oz, 0.f};
    o[4] = (f32x4){Cbx, Cby, Cbz, 0.f};
    *(f32x4*)(capack4 + (size_t)idx * 4) = (f32x4){Cax, Cay, Caz, 0.f};
  }
}

// exclusive block scan over 256 threads
__device__ __forceinline__ u32 blockExclScan(u32 v, u32* scanw, int t) {
  int lane = t & 63, w = t >> 6;
  u32 inc = v;
#pragma unroll
  for (int off = 1; off < 64; off <<= 1) {
    u32 o = __shfl_up(inc, off);
    if (lane >= off) inc += o;
  }
  if (lane == 63) scanw[w] = inc;
  __syncthreads();
  u32 base = 0;
  for (int ww = 0; ww < w; ++ww) base += scanw[ww];
  __syncthreads();
  return base + inc - v;
}

template<int NB, bool CHKPREF>
__device__ __forceinline__ void radix_round(u32* hist, u32* scanw, u32* selinfo, int t,
                                            const u32* kv, u32 pref, int prefShift,
                                            int binShift, u32 binMask, u32 r) {
  const int PB = NB / 256;
#pragma unroll
  for (int q = 0; q < PB / 4; ++q)
    *(u32x4*)&hist[t * PB + q * 4] = (u32x4){0, 0, 0, 0};
  __syncthreads();
#pragma unroll
  for (int s = 0; s < 8; ++s) {
    bool ok = (!CHKPREF) || ((kv[s] >> prefShift) == pref);
    if (ok) atomicAdd(&hist[(kv[s] >> binShift) & binMask], 1u);
  }
  __syncthreads();
  u32 loc[PB];
  u32 sum = 0;
#pragma unroll
  for (int q = 0; q < PB / 4; ++q) {
    u32x4 lv = *(u32x4*)&hist[t * PB + q * 4];
    loc[q * 4 + 0] = lv.x; loc[q * 4 + 1] = lv.y;
    loc[q * 4 + 2] = lv.z; loc[q * 4 + 3] = lv.w;
    sum += lv.x + lv.y + lv.z + lv.w;
  }
  int lane = t & 63, w = t >> 6;
  u32 inc = sum;
#pragma unroll
  for (int off = 1; off < 64; off <<= 1) {
    u32 o = __shfl_up(inc, off);
    if (lane >= off) inc += o;
  }
  if (lane == 63) scanw[w] = inc;
  __syncthreads();
  u32 base = 0;
  for (int ww = 0; ww < w; ++ww) base += scanw[ww];
  u32 c = base + inc - sum;
#pragma unroll
  for (int q = 0; q < PB; ++q) {
    u32 nc = c + loc[q];
    if (c < r && r <= nc) { selinfo[0] = (u32)(t * PB + q); selinfo[1] = r - c; }
    c = nc;
  }
  __syncthreads();
}

// ---------------- top-48 per row: exact radix select ----------------
__global__ __launch_bounds__(256) void topk_kernel(const float* __restrict__ capack4,
                                                   const float* __restrict__ mask,
                                                   float* __restrict__ dtop,
                                                   float* __restrict__ eidx_f) {
  __shared__ u32 hist[4096];
  __shared__ u32 scanw[4];
  __shared__ u32 selinfo[2];
  __shared__ float redf[4];
  __shared__ u64 win[64];

  int row = blockIdx.x;
  int b = row >> 11, i = row & (NN - 1);
  int t = threadIdx.x, lane = t & 63, w = t >> 6;
  const float* cab4 = capack4 + (size_t)b * NN * 4;
  const float* mrow = mask + (size_t)b * NN;
  f32x4 ci = *(const f32x4*)&cab4[(size_t)i * 4];
  float mi = mrow[i];
  f32x4 mk0 = *(const f32x4*)&mrow[t * 8];
  f32x4 mk1 = *(const f32x4*)&mrow[t * 8 + 4];

  float dvv[8], m2v[8];
  float lmax = 0.f;
#pragma unroll
  for (int s = 0; s < 8; ++s) {
    f32x4 cj = *(const f32x4*)&cab4[(size_t)(t * 8 + s) * 4];
    float dx = ci.x - cj.x, dy = ci.y - cj.y, dz = ci.z - cj.z;
    float d = sqrtf(dx * dx + dy * dy + dz * dz + 1e-6f);
    float mj = (s < 4) ? mk0[s] : mk1[s - 4];
    float m2 = mi * mj;
    float D = m2 * d;
    dvv[s] = D; m2v[s] = m2;
    lmax = fmaxf(lmax, D);
  }
#pragma unroll
  for (int off = 32; off >= 1; off >>= 1) lmax = fmaxf(lmax, __shfl_xor(lmax, off));
  if (lane == 0) redf[w] = lmax;
  __syncthreads();
  float rmax = fmaxf(fmaxf(redf[0], redf[1]), fmaxf(redf[2], redf[3]));

  u32 kv[8];
#pragma unroll
  for (int s = 0; s < 8; ++s)
    kv[s] = __float_as_uint(dvv[s] + (1.0f - m2v[s]) * rmax);

  u32 r = KTOP;
  radix_round<4096, false>(hist, scanw, selinfo, t, kv, 0, 0, 20, 0xFFFu, r);
  u32 sel1 = selinfo[0]; r = selinfo[1];
  radix_round<1024, true>(hist, scanw, selinfo, t, kv, sel1, 20, 10, 0x3FFu, r);
  u32 sel2 = selinfo[0]; r = selinfo[1];
  u32 pref12 = (sel1 << 10) | sel2;
  radix_round<1024, true>(hist, scanw, selinfo, t, kv, pref12, 10, 0, 0x3FFu, r);
  u32 sel3 = selinfo[0];
  u32 takeEq = selinfo[1];
  u32 T = (sel1 << 20) | (sel2 << 10) | sel3;

  u32 lcnt = 0, ecnt = 0;
#pragma unroll
  for (int s = 0; s < 8; ++s) { lcnt += (kv[s] < T); ecnt += (kv[s] == T); }
  u32 ebase = blockExclScan(ecnt, scanw, t);
  u32 taken = 0;
  if (ebase < takeEq) { u32 room = takeEq - ebase; taken = room < ecnt ? room : ecnt; }
  u32 wbase = blockExclScan(lcnt + taken, scanw, t);
  u32 slot = wbase, tleft = taken;
#pragma unroll
  for (int s = 0; s < 8; ++s) {
    u32 j = (u32)(t * 8 + s);
    if (kv[s] < T) {
      win[slot++] = ((u64)kv[s] << 32) | j;
    } else if (kv[s] == T && tleft) {
      win[slot++] = ((u64)kv[s] << 32) | j;
      tleft--;
    }
  }
  __syncthreads();

  if (w == 0) {
    u64 key = (lane < KTOP) ? win[lane] : ~0ull;
#pragma unroll
    for (int k = 2; k <= 64; k <<= 1) {
#pragma unroll
      for (int jj = k >> 1; jj >= 1; jj >>= 1) {
        u64 p = __shfl_xor(key, jj);
        bool lowerl = (lane & jj) == 0;
        bool asc = (lane & k) == 0;
        u64 mn = p < key ? p : key;
        u64 mx = p < key ? key : p;
        key = (lowerl == asc) ? mn : mx;
      }
    }
    if (lane < KTOP) {
      u32 j = (u32)(key & 0xffffffffu);
      eidx_f[row * KTOP + lane] = (float)j;
      dtop[row * KTOP + lane] = __uint_as_float((u32)(key >> 32));
    }
  }
}

// RBF 8-vector -> packed fp8 e4m3 (geometric recurrence + 4 hw pack ops)
__device__ __forceinline__ long rbf8f8(float D, float mu0) {
  float Dc = fminf(D, 40.0f);
  float t0 = (Dc - mu0) * 0.8f;
  float v0 = __expf(-t0 * t0);
  float g = __expf(fmaf(2.13333333f, t0, -1.13777778f));
  const float C = 0.10273985f;
  float v1 = v0 * g; g *= C;
  float v2 = v1 * g; g *= C;
  float v3 = v2 * g; g *= C;
  float v4 = v3 * g; g *= C;
  float v5 = v4 * g; g *= C;
  float v6 = v5 * g; g *= C;
  float v7 = v6 * g;
  u32 lo = cvtpk_fp8(v0, v1, 0u, false);
  lo = cvtpk_fp8(v2, v3, lo, true);
  u32 hi = cvtpk_fp8(v4, v5, 0u, false);
  hi = cvtpk_fp8(v6, v7, hi, true);
  return (long)(((u64)hi << 32) | lo);
}

// ---------------- edge: one wave per (residue, m-tile); fp8 GEMM; R6 structure ----------------
// 16x128 output per wave, acc[8]=32 regs, D in wave-private LDS, zero barriers.
// fp8 halves B traffic (52KB/wave) and A-pack width; MFMA rate = bf16 rate.
__global__ __launch_bounds__(64, 5) void edge_kernel(const float* __restrict__ atoms5p,
                                                     const u8* __restrict__ wtf8,
                                                     const float* __restrict__ eidx_f,
                                                     const float* __restrict__ dtop,
                                                     const int* __restrict__ Ridx,
                                                     const int* __restrict__ chains,
                                                     const float* __restrict__ Wpos,
                                                     const float* __restrict__ bpos,
                                                     const float* __restrict__ bedge,
                                                     float* __restrict__ Eout) {
  __shared__ float D_lds[16][26];   // p=0: dtop; p=1..24 pair dists
  __shared__ u32 pos_lds[16][4];    // positional cols 0..15, packed fp8 (16 bytes/row)
  __shared__ int jbuf[16];
  __shared__ f32x4 aI_lds[5];

  int lane = threadIdx.x;
  int bid = blockIdx.x;
  int row = bid / 3, mt = bid - row * 3;   // 3 m-tiles per residue
  int b = row >> 11, i = row & (NN - 1);
  int kbase = mt * 16;
  const float* atomsB = atoms5p + (size_t)b * NN * 20;

  if (lane < 5) aI_lds[lane] = *(const f32x4*)&atomsB[(size_t)i * 20 + lane * 4];
  if (lane < 16) {
    int k = kbase + lane;
    int j = (int)eidx_f[(size_t)row * KTOP + k];
    jbuf[lane] = j;
    D_lds[lane][0] = dtop[(size_t)row * KTOP + k];
    int Ri = Ridx[b * NN + i], Rj = Ridx[b * NN + j];
    int same = (chains[b * NN + i] == chains[b * NN + j]);
    int off = Ri - Rj + 32;
    off = off < 0 ? 0 : (off > 64 ? 64 : off);
    int drow = same ? off : 65;
    const float* wr = Wpos + drow * 16;
    f32x4 w0 = *(const f32x4*)&wr[0];
    f32x4 w1 = *(const f32x4*)&wr[4];
    f32x4 w2 = *(const f32x4*)&wr[8];
    f32x4 w3 = *(const f32x4*)&wr[12];
    f32x4 b0 = *(const f32x4*)&bpos[0];
    f32x4 b1 = *(const f32x4*)&bpos[4];
    f32x4 b2 = *(const f32x4*)&bpos[8];
    f32x4 b3 = *(const f32x4*)&bpos[12];
    u32 q0 = cvtpk_fp8(w0.x + b0.x, w0.y + b0.y, 0u, false);
    q0 = cvtpk_fp8(w0.z + b0.z, w0.w + b0.w, q0, true);
    u32 q1 = cvtpk_fp8(w1.x + b1.x, w1.y + b1.y, 0u, false);
    q1 = cvtpk_fp8(w1.z + b1.z, w1.w + b1.w, q1, true);
    u32 q2 = cvtpk_fp8(w2.x + b2.x, w2.y + b2.y, 0u, false);
    q2 = cvtpk_fp8(w2.z + b2.z, w2.w + b2.w, q2, true);
    u32 q3 = cvtpk_fp8(w3.x + b3.x, w3.y + b3.y, 0u, false);
    q3 = cvtpk_fp8(w3.z + b3.z, w3.w + b3.w, q3, true);
    pos_lds[lane][0] = q0;
    pos_lds[lane][1] = q1;
    pos_lds[lane][2] = q2;
    pos_lds[lane][3] = q3;
  }

  // 384 pair distances for this wave's 16 neighbors (6 per lane; wave-private -> no barrier)
#pragma unroll
  for (int q = 0; q < 6; ++q) {
    int e = q * 64 + lane;
    int kl = e / 24;
    int p = e - kl * 24 + 1;
    int j = jbuf[kl];
    f32x4 I = aI_lds[cPA[p]];
    f32x4 J = *(const f32x4*)&atomsB[(size_t)j * 20 + cPB[p] * 4];
    float dx = I.x - J.x, dy = I.y - J.y, dz = I.z - J.z;
    D_lds[kl][p] = __builtin_amdgcn_sqrtf(dx * dx + dy * dy + dz * dz + 1e-6f);
  }

  // GEMM: C(16x128) = A(16x416) B(416x128) in fp8; 8 n-tiles x 13 k-steps
  int lr = lane & 15, lg = lane >> 4;
  const u8* wk = wtf8 + (size_t)lg * 1024 + lr * 8;
  const float MU8 = 12.6666667f;
  f32x4 acc[8] = {};

  {  // kc = 0: cols 0..15 positional, 16..31 RBF p=0 (dtop)
    long af;
    if (lg < 2) {
      af = *(const long*)&pos_lds[lr][lg * 2];
    } else {
      af = rbf8f8(D_lds[lr][0], (lg == 2) ? 2.0f : MU8);
    }
#pragma unroll
    for (int nt = 0; nt < 8; ++nt) {
      long bv = *(const long*)(wk + nt * 128);
      acc[nt] = __builtin_amdgcn_mfma_f32_16x16x32_fp8_fp8(af, bv, acc[nt], 0, 0, 0);
    }
  }
#pragma unroll
  for (int kc = 1; kc < 13; ++kc) {
    int p = 2 * kc - 1 + (lg >> 1);
    float mu0 = (lg & 1) ? MU8 : 2.0f;
    long af = rbf8f8(D_lds[lr][p], mu0);
    const u8* wkc = wk + (size_t)kc * 4096;
#pragma unroll
    for (int nt = 0; nt < 8; ++nt) {
      long bv = *(const long*)(wkc + nt * 128);
      acc[nt] = __builtin_amdgcn_mfma_f32_16x16x32_fp8_fp8(af, bv, acc[nt], 0, 0, 0);
    }
  }

  // epilogue: bias + direct stores (16-lane groups write 64B contiguous)
  float bias[8];
#pragma unroll
  for (int nt = 0; nt < 8; ++nt) bias[nt] = bedge[nt * 16 + lr];
  float* orow = Eout + ((size_t)row * KTOP + kbase) * EF;
#pragma unroll
  for (int qq = 0; qq < 4; ++qq) {
    float* pr = orow + (size_t)(lg * 4 + qq) * EF + lr;
#pragma unroll
    for (int nt = 0; nt < 8; ++nt)
      pr[nt * 16] = acc[nt][qq] + bias[nt];
  }
}

extern "C" void kernel_launch(void* const* d_in, const int* in_sizes, int n_in,
                              void* d_out, int out_size, void* d_ws, size_t ws_size,
                              hipStream_t stream) {
  const float* X = (const float*)d_in[0];
  const float* mask = (const float*)d_in[1];
  const int* Ridx = (const int*)d_in[2];
  const int* chains = (const int*)d_in[3];
  const float* Wpos = (const float*)d_in[4];
  const float* bpos = (const float*)d_in[5];
  const float* Wedge = (const float*)d_in[6];
  const float* bedge = (const float*)d_in[7];

  float* Eout = (float*)d_out;
  float* EidxF = Eout + (size_t)BN * KTOP * EF;

  u8* wtf8 = (u8*)d_ws;                                    // 53248 bytes
  float* atoms5p = (float*)((char*)d_ws + 53248);          // BN*20 f32
  float* capack4 = atoms5p + (size_t)BN * 20;              // BN*4 f32
  float* dtop = capack4 + (size_t)BN * 4;                  // BN*48 f32

  int prep_threads = EIN * EF / 4 + BN;
  prep_kernel<<<(prep_threads + 255) / 256, 256, 0, stream>>>(X, Wedge, atoms5p, capack4, wtf8);
  topk_kernel<<<BN, 256, 0, stream>>>(capack4, mask, dtop, EidxF);
  edge_kernel<<<BN * 3, 64, 0, stream>>>(atoms5p, wtf8, EidxF, dtop, Ridx, chains, Wpos, bpos, bedge, Eout);
}